// Round 2
// baseline (325.964 us; speedup 1.0000x reference)
//
#include <hip/hip_runtime.h>
#include <math.h>

// Problem dims (hardcoded from reference):
//   B=16, C=256, H=W=128
#define BATCHES      16
#define CHANNELS     256
#define HW           (128 * 128)                 // 16384 floats per channel
#define PER_BATCH    (CHANNELS * HW)             // 4,194,304 floats per (input,batch)
#define VEC_PER_BATCH (PER_BATCH / 4)            // 1,048,576 float4
#define BLOCKS_PER_BN 64
#define RTHREADS      256
#define CHUNK_VECS    (VEC_PER_BATCH / BLOCKS_PER_BN)   // 16384 float4 = 4 channels

// ws layout (floats): [0 .. 3071] partials (3 inputs * 16 batches * 64 blocks)
//                     [3072 .. 3119] attention scalars (3*16)
#define PARTIALS_OFF 0
#define ATT_OFF      (3 * BATCHES * BLOCKS_PER_BN)

// ---------------------------------------------------------------------------
// Kernel 1: per-block weighted partial sums.
// grid.x = 3 * 16 * 64.  blk = which*16*64 + batch*64 + chunk.
// Each block covers a contiguous 16384-float4 slice (= exactly 4 channels)
// of one (input,batch). Weights hoisted to registers; 4 spans of 16
// fully-unrolled float4 loads each -> deep MLP, no LDS in the hot loop.
// ---------------------------------------------------------------------------
__global__ __launch_bounds__(RTHREADS) void fusion_reduce_kernel(
    const float* __restrict__ gray,
    const float* __restrict__ green,
    const float* __restrict__ rgb,
    const float* __restrict__ conv_w,
    float* __restrict__ partials)
{
    int blk   = blockIdx.x;
    int chunk = blk & (BLOCKS_PER_BN - 1);
    int bn    = blk >> 6;                 // which*16 + batch
    int batch = bn & (BATCHES - 1);
    int which = bn >> 4;

    const float* x = (which == 0) ? gray : (which == 1) ? green : rgb;
    const float4* xv = reinterpret_cast<const float4*>(x) +
                       (size_t)batch * VEC_PER_BATCH + (size_t)chunk * CHUNK_VECS;

    // 4 channels per chunk; weights are wave-uniform scalars.
    int ch0 = chunk * 4;
    float w0 = conv_w[ch0 + 0];
    float w1 = conv_w[ch0 + 1];
    float w2 = conv_w[ch0 + 2];
    float w3 = conv_w[ch0 + 3];

    // span sp covers float4 indices [sp*4096, (sp+1)*4096) = channel ch0+sp
    float s[4];
    #pragma unroll
    for (int sp = 0; sp < 4; ++sp) {
        const float4* p = xv + sp * 4096 + threadIdx.x;
        float acc = 0.0f;
        #pragma unroll
        for (int i = 0; i < 16; ++i) {
            float4 d = p[i * RTHREADS];
            acc += (d.x + d.y) + (d.z + d.w);
        }
        s[sp] = acc;
    }
    float sum = s[0] * w0 + s[1] * w1 + s[2] * w2 + s[3] * w3;

    // wave64 tree reduce
    #pragma unroll
    for (int off = 32; off > 0; off >>= 1) sum += __shfl_down(sum, off, 64);

    __shared__ float s4[RTHREADS / 64];
    int wid = threadIdx.x >> 6;
    if ((threadIdx.x & 63) == 0) s4[wid] = sum;
    __syncthreads();
    if (threadIdx.x == 0) {
        partials[blk] = (s4[0] + s4[1]) + (s4[2] + s4[3]);
    }
}

// ---------------------------------------------------------------------------
// Kernel 2: reduce 64 partials per (input,batch) -> sigmoid attention scalar.
// grid.x = 48, block = 64.
// ---------------------------------------------------------------------------
__global__ __launch_bounds__(64) void fusion_att_kernel(
    const float* __restrict__ partials,
    const float* __restrict__ conv_b,
    float* __restrict__ att)
{
    int row = blockIdx.x;                  // which*16 + batch
    float v = partials[row * BLOCKS_PER_BN + (int)threadIdx.x];
    #pragma unroll
    for (int off = 32; off > 0; off >>= 1) v += __shfl_down(v, off, 64);
    if (threadIdx.x == 0) {
        float logit = v * (1.0f / (float)HW) + conv_b[0];
        att[row] = 1.0f / (1.0f + expf(-logit));
    }
}

// ---------------------------------------------------------------------------
// Kernel 3: apply attention and fuse.
// out = gray*a_g + 10*(green*a_gr + rgb*a_r), float4 granularity.
// ---------------------------------------------------------------------------
__global__ __launch_bounds__(RTHREADS) void fusion_apply_kernel(
    const float4* __restrict__ gray,
    const float4* __restrict__ green,
    const float4* __restrict__ rgb,
    const float* __restrict__ att,
    float4* __restrict__ out)
{
    size_t i = (size_t)blockIdx.x * RTHREADS + threadIdx.x;
    int b = (int)(i >> 20);                // VEC_PER_BATCH = 2^20
    float ag  = att[b];
    float agr = att[BATCHES + b];
    float ar  = att[2 * BATCHES + b];

    float4 dg = gray[i], dn = green[i], dr = rgb[i];
    float4 o;
    o.x = dg.x * ag + 10.0f * (dn.x * agr + dr.x * ar);
    o.y = dg.y * ag + 10.0f * (dn.y * agr + dr.y * ar);
    o.z = dg.z * ag + 10.0f * (dn.z * agr + dr.z * ar);
    o.w = dg.w * ag + 10.0f * (dn.w * agr + dr.w * ar);
    out[i] = o;
}

extern "C" void kernel_launch(void* const* d_in, const int* in_sizes, int n_in,
                              void* d_out, int out_size, void* d_ws, size_t ws_size,
                              hipStream_t stream) {
    const float* gray   = (const float*)d_in[0];
    const float* green  = (const float*)d_in[1];
    const float* rgb    = (const float*)d_in[2];
    const float* conv_w = (const float*)d_in[3];
    const float* conv_b = (const float*)d_in[4];
    float* out = (float*)d_out;
    float* ws  = (float*)d_ws;

    float* partials = ws + PARTIALS_OFF;   // 3072 floats
    float* att      = ws + ATT_OFF;        // 48 floats

    // Pass 1: weighted partial sums (reads all 3 inputs once)
    fusion_reduce_kernel<<<3 * BATCHES * BLOCKS_PER_BN, RTHREADS, 0, stream>>>(
        gray, green, rgb, conv_w, partials);

    // Pass 2: finish reduction + sigmoid (48 scalars)
    fusion_att_kernel<<<3 * BATCHES, 64, 0, stream>>>(partials, conv_b, att);

    // Pass 3: apply + fuse (reads all 3 inputs again, writes output)
    int total_vec = BATCHES * VEC_PER_BATCH;     // 16,777,216
    fusion_apply_kernel<<<total_vec / RTHREADS, RTHREADS, 0, stream>>>(
        (const float4*)gray, (const float4*)green, (const float4*)rgb,
        att, (float4*)out);
}

// Round 5
// 312.051 us; speedup vs baseline: 1.0446x; 1.0446x over previous
//
#include <hip/hip_runtime.h>
#include <math.h>

// Problem dims (hardcoded from reference):
//   B=16, C=256, H=W=128
#define BATCHES      16
#define CHANNELS     256
#define HW           (128 * 128)                 // 16384 floats per channel
#define PER_BATCH    (CHANNELS * HW)             // 4,194,304 floats per (input,batch)
#define VEC_PER_BATCH (PER_BATCH / 4)            // 1,048,576 float4
#define RTHREADS      256

// Reduce geometry: 32 "pairs" per (input,batch); each pair = 8 channels =
// 32768 float4 = 512 KB. grid = 3*16*32 = 1536 blocks -> 6 blocks/CU,
// all co-resident (one uniform round, no tail).
#define PAIRS_PER_BN  32
#define PAIR_VECS     (VEC_PER_BATCH / PAIRS_PER_BN)    // 32768 float4
#define REDUCE_BLOCKS (3 * BATCHES * PAIRS_PER_BN)      // 1536

// ws layout (floats): [0 .. 1535] partials, [1536 .. 1583] attention scalars
#define PARTIALS_OFF 0
#define ATT_OFF      REDUCE_BLOCKS

typedef float f32x4 __attribute__((ext_vector_type(4)));

// ---------------------------------------------------------------------------
// Kernel 1: per-block weighted partial sums.
// blk = which*16*32 + batch*32 + pair. Each block covers 8 contiguous
// channels (32768 float4) of one (input,batch). Weights in registers,
// 8 spans of 16 fully-unrolled float4 loads.
// ---------------------------------------------------------------------------
__global__ __launch_bounds__(RTHREADS) void fusion_reduce_kernel(
    const float* __restrict__ gray,
    const float* __restrict__ green,
    const float* __restrict__ rgb,
    const float* __restrict__ conv_w,
    float* __restrict__ partials)
{
    int blk   = blockIdx.x;
    int pair  = blk & (PAIRS_PER_BN - 1);
    int bn    = blk >> 5;                 // which*16 + batch
    int batch = bn & (BATCHES - 1);
    int which = bn >> 4;

    const float* x = (which == 0) ? gray : (which == 1) ? green : rgb;
    const float4* xv = reinterpret_cast<const float4*>(x) +
                       (size_t)batch * VEC_PER_BATCH + (size_t)pair * PAIR_VECS;

    int ch0 = pair * 8;                   // 8 channels per pair
    float w[8];
    #pragma unroll
    for (int c = 0; c < 8; ++c) w[c] = conv_w[ch0 + c];

    // span sp = channel ch0+sp, covering float4 [sp*4096, (sp+1)*4096)
    float sum = 0.0f;
    #pragma unroll
    for (int sp = 0; sp < 8; ++sp) {
        const float4* p = xv + sp * 4096 + threadIdx.x;
        float acc = 0.0f;
        #pragma unroll
        for (int i = 0; i < 16; ++i) {
            float4 d = p[i * RTHREADS];
            acc += (d.x + d.y) + (d.z + d.w);
        }
        sum += acc * w[sp];
    }

    // wave64 tree reduce
    #pragma unroll
    for (int off = 32; off > 0; off >>= 1) sum += __shfl_down(sum, off, 64);

    __shared__ float s4[RTHREADS / 64];
    int wid = threadIdx.x >> 6;
    if ((threadIdx.x & 63) == 0) s4[wid] = sum;
    __syncthreads();
    if (threadIdx.x == 0) {
        partials[blk] = (s4[0] + s4[1]) + (s4[2] + s4[3]);
    }
}

// ---------------------------------------------------------------------------
// Kernel 2: reduce 32 partials per (input,batch) -> sigmoid attention scalar.
// grid.x = 48, block = 64 (lanes >= 32 contribute 0).
// ---------------------------------------------------------------------------
__global__ __launch_bounds__(64) void fusion_att_kernel(
    const float* __restrict__ partials,
    const float* __restrict__ conv_b,
    float* __restrict__ att)
{
    int row = blockIdx.x;                  // which*16 + batch
    float v = (threadIdx.x < PAIRS_PER_BN)
                ? partials[row * PAIRS_PER_BN + (int)threadIdx.x] : 0.0f;
    #pragma unroll
    for (int off = 16; off > 0; off >>= 1) v += __shfl_down(v, off, 64);
    if (threadIdx.x == 0) {
        float logit = v * (1.0f / (float)HW) + conv_b[0];
        att[row] = 1.0f / (1.0f + expf(-logit));
    }
}

// ---------------------------------------------------------------------------
// Kernel 3: apply attention and fuse.
// out = gray*a_g + 10*(green*a_gr + rgb*a_r), float4 granularity.
// Non-temporal store: output is never re-read; keep inputs resident in L3.
// ---------------------------------------------------------------------------
__global__ __launch_bounds__(RTHREADS) void fusion_apply_kernel(
    const float4* __restrict__ gray,
    const float4* __restrict__ green,
    const float4* __restrict__ rgb,
    const float* __restrict__ att,
    float4* __restrict__ out)
{
    size_t i = (size_t)blockIdx.x * RTHREADS + threadIdx.x;
    int b = (int)(i >> 20);                // VEC_PER_BATCH = 2^20
    float ag  = att[b];
    float agr = att[BATCHES + b];
    float ar  = att[2 * BATCHES + b];

    float4 dg = gray[i], dn = green[i], dr = rgb[i];
    f32x4 o;
    o.x = dg.x * ag + 10.0f * (dn.x * agr + dr.x * ar);
    o.y = dg.y * ag + 10.0f * (dn.y * agr + dr.y * ar);
    o.z = dg.z * ag + 10.0f * (dn.z * agr + dr.z * ar);
    o.w = dg.w * ag + 10.0f * (dn.w * agr + dr.w * ar);
    __builtin_nontemporal_store(o, reinterpret_cast<f32x4*>(&out[i]));
}

extern "C" void kernel_launch(void* const* d_in, const int* in_sizes, int n_in,
                              void* d_out, int out_size, void* d_ws, size_t ws_size,
                              hipStream_t stream) {
    const float* gray   = (const float*)d_in[0];
    const float* green  = (const float*)d_in[1];
    const float* rgb    = (const float*)d_in[2];
    const float* conv_w = (const float*)d_in[3];
    const float* conv_b = (const float*)d_in[4];
    float* out = (float*)d_out;
    float* ws  = (float*)d_ws;

    float* partials = ws + PARTIALS_OFF;   // 1536 floats
    float* att      = ws + ATT_OFF;        // 48 floats

    // Pass 1: weighted partial sums (reads all 3 inputs once)
    fusion_reduce_kernel<<<REDUCE_BLOCKS, RTHREADS, 0, stream>>>(
        gray, green, rgb, conv_w, partials);

    // Pass 2: finish reduction + sigmoid (48 scalars)
    fusion_att_kernel<<<3 * BATCHES, 64, 0, stream>>>(partials, conv_b, att);

    // Pass 3: apply + fuse (reads all 3 inputs again, writes output)
    int total_vec = BATCHES * VEC_PER_BATCH;     // 16,777,216
    fusion_apply_kernel<<<total_vec / RTHREADS, RTHREADS, 0, stream>>>(
        (const float4*)gray, (const float4*)green, (const float4*)rgb,
        att, (float4*)out);
}

// Round 6
// 310.961 us; speedup vs baseline: 1.0482x; 1.0035x over previous
//
#include <hip/hip_runtime.h>
#include <math.h>

// Problem dims (hardcoded from reference):
//   B=16, C=256, H=W=128
#define BATCHES      16
#define CHANNELS     256
#define HW           (128 * 128)                 // 16384 floats per channel
#define PER_BATCH    (CHANNELS * HW)             // 4,194,304 floats per (input,batch)
#define VEC_PER_BATCH (PER_BATCH / 4)            // 1,048,576 float4 (2^20)
#define RTHREADS      256

// Reduce geometry (apply-like shape): each block = 256 threads x 4 float4
//   = 1024 float4 = 4096 floats = exactly ONE channel of one (input,batch).
// Blocks per input = 2^24 / 1024 = 16384; total = 3*16384 = 49152.
// Global block g: which = g>>14, bn(row) = g>>10, partial slot = g.
#define K1_BLOCKS     49152
#define VECS_PER_K1   1024                        // float4 per block
#define PARTS_PER_ROW 1024                        // partials per (which,batch)

// ws layout (floats): [0 .. 49151] partials, [49152 .. 49199] att scalars
#define PARTIALS_OFF 0
#define ATT_OFF      K1_BLOCKS

typedef float f32x4 __attribute__((ext_vector_type(4)));

// ---------------------------------------------------------------------------
// Kernel 1: per-block weighted partial sums, apply-like memory shape.
// 4 independent float4 loads per thread, tiny VGPR, 49152 blocks.
// ---------------------------------------------------------------------------
__global__ __launch_bounds__(RTHREADS) void fusion_reduce_kernel(
    const float* __restrict__ gray,
    const float* __restrict__ green,
    const float* __restrict__ rgb,
    const float* __restrict__ conv_w,
    float* __restrict__ partials)
{
    int g     = blockIdx.x;
    int which = g >> 14;                      // 16384 blocks per input
    int inner = g & 16383;
    size_t base = (size_t)inner * VECS_PER_K1;  // float4 index within input

    const float* x = (which == 0) ? gray : (which == 1) ? green : rgb;
    const float4* xv = reinterpret_cast<const float4*>(x) + base;

    // whole block lies in one channel: ch = (base>>12) & 255 (wave-uniform)
    float w = conv_w[(int)((base >> 12) & (CHANNELS - 1))];

    float4 d0 = xv[threadIdx.x + 0 * RTHREADS];
    float4 d1 = xv[threadIdx.x + 1 * RTHREADS];
    float4 d2 = xv[threadIdx.x + 2 * RTHREADS];
    float4 d3 = xv[threadIdx.x + 3 * RTHREADS];
    float sum = ((d0.x + d0.y) + (d0.z + d0.w))
              + ((d1.x + d1.y) + (d1.z + d1.w))
              + ((d2.x + d2.y) + (d2.z + d2.w))
              + ((d3.x + d3.y) + (d3.z + d3.w));

    // wave64 tree reduce
    #pragma unroll
    for (int off = 32; off > 0; off >>= 1) sum += __shfl_down(sum, off, 64);

    __shared__ float s4[RTHREADS / 64];
    int wid = threadIdx.x >> 6;
    if ((threadIdx.x & 63) == 0) s4[wid] = sum;
    __syncthreads();
    if (threadIdx.x == 0) {
        partials[g] = ((s4[0] + s4[1]) + (s4[2] + s4[3])) * w;
    }
}

// ---------------------------------------------------------------------------
// Kernel 2: fold 1024 partials per (which,batch) -> sigmoid attention scalar.
// grid.x = 48, block = 256; 4 partials per thread.
// ---------------------------------------------------------------------------
__global__ __launch_bounds__(RTHREADS) void fusion_att_kernel(
    const float* __restrict__ partials,
    const float* __restrict__ conv_b,
    float* __restrict__ att)
{
    int row = blockIdx.x;                  // which*16 + batch
    const float* p = partials + (size_t)row * PARTS_PER_ROW;
    float v = p[threadIdx.x + 0 * RTHREADS] + p[threadIdx.x + 1 * RTHREADS]
            + p[threadIdx.x + 2 * RTHREADS] + p[threadIdx.x + 3 * RTHREADS];

    #pragma unroll
    for (int off = 32; off > 0; off >>= 1) v += __shfl_down(v, off, 64);

    __shared__ float s4[RTHREADS / 64];
    int wid = threadIdx.x >> 6;
    if ((threadIdx.x & 63) == 0) s4[wid] = v;
    __syncthreads();
    if (threadIdx.x == 0) {
        float total = (s4[0] + s4[1]) + (s4[2] + s4[3]);
        float logit = total * (1.0f / (float)HW) + conv_b[0];
        att[row] = 1.0f / (1.0f + expf(-logit));
    }
}

// ---------------------------------------------------------------------------
// Kernel 3: apply attention and fuse.
// out = gray*a_g + 10*(green*a_gr + rgb*a_r), float4 granularity.
// Non-temporal store: output is never re-read; keep inputs resident in L3.
// ---------------------------------------------------------------------------
__global__ __launch_bounds__(RTHREADS) void fusion_apply_kernel(
    const float4* __restrict__ gray,
    const float4* __restrict__ green,
    const float4* __restrict__ rgb,
    const float* __restrict__ att,
    float4* __restrict__ out)
{
    size_t i = (size_t)blockIdx.x * RTHREADS + threadIdx.x;
    int b = (int)(i >> 20);                // VEC_PER_BATCH = 2^20
    float ag  = att[b];
    float agr = att[BATCHES + b];
    float ar  = att[2 * BATCHES + b];

    float4 dg = gray[i], dn = green[i], dr = rgb[i];
    f32x4 o;
    o.x = dg.x * ag + 10.0f * (dn.x * agr + dr.x * ar);
    o.y = dg.y * ag + 10.0f * (dn.y * agr + dr.y * ar);
    o.z = dg.z * ag + 10.0f * (dn.z * agr + dr.z * ar);
    o.w = dg.w * ag + 10.0f * (dn.w * agr + dr.w * ar);
    __builtin_nontemporal_store(o, reinterpret_cast<f32x4*>(&out[i]));
}

extern "C" void kernel_launch(void* const* d_in, const int* in_sizes, int n_in,
                              void* d_out, int out_size, void* d_ws, size_t ws_size,
                              hipStream_t stream) {
    const float* gray   = (const float*)d_in[0];
    const float* green  = (const float*)d_in[1];
    const float* rgb    = (const float*)d_in[2];
    const float* conv_w = (const float*)d_in[3];
    const float* conv_b = (const float*)d_in[4];
    float* out = (float*)d_out;
    float* ws  = (float*)d_ws;

    float* partials = ws + PARTIALS_OFF;   // 49152 floats (192 KB)
    float* att      = ws + ATT_OFF;        // 48 floats

    // Pass 1: weighted partial sums (reads all 3 inputs once)
    fusion_reduce_kernel<<<K1_BLOCKS, RTHREADS, 0, stream>>>(
        gray, green, rgb, conv_w, partials);

    // Pass 2: fold partials + sigmoid (48 scalars)
    fusion_att_kernel<<<3 * BATCHES, RTHREADS, 0, stream>>>(
        partials, conv_b, att);

    // Pass 3: apply + fuse (reads all 3 inputs again, writes output)
    int total_vec = BATCHES * VEC_PER_BATCH;     // 16,777,216
    fusion_apply_kernel<<<total_vec / RTHREADS, RTHREADS, 0, stream>>>(
        (const float4*)gray, (const float4*)green, (const float4*)rgb,
        att, (float4*)out);
}